// Round 15
// baseline (535.323 us; speedup 1.0000x reference)
//
#include <hip/hip_runtime.h>

#define LQN 2046
#define LL  2048
#define CC  512
#define DD  64

typedef float  f32x4 __attribute__((ext_vector_type(4)));
typedef float  f32x2 __attribute__((ext_vector_type(2)));
typedef __bf16 b16x8 __attribute__((ext_vector_type(8)));
typedef unsigned int u32x4 __attribute__((ext_vector_type(4)));
typedef unsigned int u32x2 __attribute__((ext_vector_type(2)));

static __device__ __forceinline__ unsigned short f2bf(float f) {
  union { float f; unsigned u; } v; v.f = f;
  return (unsigned short)((v.u + 0x7fffu + ((v.u >> 16) & 1u)) >> 16);
}

static __device__ __forceinline__ unsigned cvtpk(float lo, float hi) {
  unsigned r;
  asm("v_cvt_pk_bf16_f32 %0, %1, %2" : "=v"(r) : "v"(lo), "v"(hi));
  return r;
}

static __device__ __forceinline__ f32x4 mfma16(b16x8 a, b16x8 b, f32x4 c) {
  return __builtin_amdgcn_mfma_f32_16x16x32_bf16(a, b, c, 0, 0, 0);
}

// async global->LDS, 16B per lane; LDS dest = wave-uniform base + lane*16
static __device__ __forceinline__ void glds16(const unsigned short* g, unsigned short* l) {
  __builtin_amdgcn_global_load_lds(
      (const __attribute__((address_space(1))) unsigned int*)(g),
      (__attribute__((address_space(3))) unsigned int*)(l),
      16, 0, 0);
}

// ---------------- Kernel 1: grouped-conv QKV projections (MFMA) --------------
// Q is pre-scaled by log2(e)/sqrt(H) so attention scores land in exp2 domain.
__global__ __launch_bounds__(256) void conv_qkv_kernel(
    const float* __restrict__ in, const float* __restrict__ qw,
    const float* __restrict__ kw, const float* __restrict__ vw,
    unsigned short* __restrict__ qo, unsigned short* __restrict__ ko,
    unsigned short* __restrict__ vo)
{
  __shared__ __align__(16) unsigned short inT[130 * 72];  // [t][ci] bf16, pad 72
  __shared__ __align__(16) unsigned short buf[128 * 72];  // transpose buffer

  const int tile = blockIdx.x, g = blockIdx.y, b = blockIdx.z;
  const int t0 = tile * 128;
  const int tid = threadIdx.x;
  const int lane = tid & 63;
  const int wv = tid >> 6;
  const int r0 = lane & 15, qh = lane >> 4;

  {
    const int ci = tid & 63, ch = tid >> 6;
    const float* src = in + ((size_t)(b * CC + g * 64 + ci)) * LL;
    #pragma unroll
    for (int i = 0; i < 8; ++i) {
      int t = ch * 32 + i * 4;
      f32x4 d = *(const f32x4*)(src + t0 + t);
      inT[(t + 0) * 72 + ci] = f2bf(d.x);
      inT[(t + 1) * 72 + ci] = f2bf(d.y);
      inT[(t + 2) * 72 + ci] = f2bf(d.z);
      inT[(t + 3) * 72 + ci] = f2bf(d.w);
    }
    if (ch == 0) {
      #pragma unroll
      for (int e = 0; e < 2; ++e) {
        int t = 128 + e;
        int tg = t0 + t; if (tg > LL - 1) tg = LL - 1;
        inT[t * 72 + ci] = f2bf(src[tg]);
      }
    }
  }
  __syncthreads();

  const float* wptr[3] = {qw, kw, vw};
  const f32x4 zero4 = {0.f, 0.f, 0.f, 0.f};

  for (int p = 0; p < 3; ++p) {
    b16x8 aW[6];
    {
      const float* wb = wptr[p] + (size_t)(g * 64 + wv * 16 + r0) * 192;
      #pragma unroll
      for (int kc = 0; kc < 6; ++kc) {
        const int ktap = kc >> 1;
        const int cib = (kc & 1) * 32 + qh * 8;
        union { b16x8 v; unsigned short u[8]; } fr;
        #pragma unroll
        for (int j = 0; j < 8; ++j)
          fr.u[j] = f2bf(wb[(cib + j) * 3 + ktap]);
        aW[kc] = fr.v;
      }
    }
    f32x4 acc[8];
    #pragma unroll
    for (int nt = 0; nt < 8; ++nt) acc[nt] = zero4;
    #pragma unroll
    for (int kc = 0; kc < 6; ++kc) {
      const int radd = kc >> 1;
      const int colh = (kc & 1) * 32 + qh * 8;
      #pragma unroll
      for (int nt = 0; nt < 8; ++nt) {
        const int trow = nt * 16 + r0 + radd;
        b16x8 bI = *(const b16x8*)&inT[trow * 72 + colh];
        acc[nt] = mfma16(aW[kc], bI, acc[nt]);
      }
    }
    __syncthreads();
    if (p < 2) {
      const float qscl = (p == 0) ? 0.51006979f : 1.0f;  // log2(e)/sqrt(8)
      #pragma unroll
      for (int nt = 0; nt < 8; ++nt) {
        const int t = nt * 16 + r0;
        #pragma unroll
        for (int r = 0; r < 4; ++r)
          buf[t * 72 + wv * 16 + qh * 4 + r] = f2bf(acc[nt][r] * qscl);
      }
      __syncthreads();
      unsigned short* dst = (p == 0 ? qo : ko) +
          ((size_t)(b * 8 + g) * LQN + t0) * DD;
      #pragma unroll
      for (int it = 0; it < 4; ++it) {
        const int id = it * 256 + tid;
        const int t = id >> 3, c8 = id & 7;
        if (t0 + t < LQN)
          *(u32x4*)(dst + t * DD + c8 * 8) = *(const u32x4*)&buf[t * 72 + c8 * 8];
      }
    } else {
      #pragma unroll
      for (int nt = 0; nt < 8; ++nt) {
        const int t = nt * 16 + r0;
        #pragma unroll
        for (int r = 0; r < 4; ++r)
          buf[(wv * 16 + qh * 4 + r) * 136 + t] = f2bf(acc[nt][r]);
      }
      __syncthreads();
      unsigned short* dst = vo + ((size_t)(b * CC + g * 64)) * LL + t0;
      #pragma unroll
      for (int it = 0; it < 4; ++it) {
        const int id = it * 256 + tid;
        const int row = id >> 4, c16 = id & 15;
        *(u32x4*)(dst + (size_t)row * LL + c16 * 8) =
            *(const u32x4*)&buf[row * 136 + c16 * 8];
      }
    }
    __syncthreads();
  }
}

// ---------------- attention pieces (deferred-PV, static-shift softmax) -------
// S^T = mfma(K,Q): lane (r0,qh) holds S[q=wv*16+r0][kv=nt*16+qh*4+rr].
// Swizzle sw = krow&7 = r0&7 (nt*16 ≡ 0 mod 8).

static __device__ __forceinline__ void qkt16(
    const unsigned short* __restrict__ Kl, bool diag, int wv, int r0, int qh,
    b16x8 aQ0, b16x8 aQ1, f32x4 (&s)[4])
{
  const int sw = r0 & 7;
  __builtin_amdgcn_s_setprio(1);
  #pragma unroll
  for (int nt = 0; nt < 4; ++nt) {
    const unsigned short* kr = Kl + (nt * 16 + r0) * 64;
    b16x8 k0 = *(const b16x8*)(kr + ((qh ^ sw) * 8));
    b16x8 k1 = *(const b16x8*)(kr + (((4 + qh) ^ sw) * 8));
    f32x4 acc = {0.f, 0.f, 0.f, 0.f};
    acc = mfma16(k0, aQ0, acc);
    s[nt] = mfma16(k1, aQ1, acc);
  }
  __builtin_amdgcn_s_setprio(0);
  if (diag) {                                 // causal: mask kv_local > q_local
    const int rowl = wv * 16 + r0;
    #pragma unroll
    for (int nt = 0; nt < 4; ++nt)
      #pragma unroll
      for (int rr = 0; rr < 4; ++rr)
        if (nt * 16 + qh * 4 + rr > rowl) s[nt][rr] = -1e30f;
  }
}

// Dual-stream QK^T: K fragments read ONCE, feed both hi and lo MFMAs.
static __device__ __forceinline__ void qkt2(
    const unsigned short* __restrict__ Kl, bool diagL, int wv, int r0, int qh,
    b16x8 aQ0h, b16x8 aQ1h, b16x8 aQ0l, b16x8 aQ1l,
    f32x4 (&sh)[4], f32x4 (&sl)[4])
{
  const int sw = r0 & 7;
  __builtin_amdgcn_s_setprio(1);
  #pragma unroll
  for (int nt = 0; nt < 4; ++nt) {
    const unsigned short* kr = Kl + (nt * 16 + r0) * 64;
    b16x8 k0 = *(const b16x8*)(kr + ((qh ^ sw) * 8));
    b16x8 k1 = *(const b16x8*)(kr + (((4 + qh) ^ sw) * 8));
    f32x4 ah = {0.f, 0.f, 0.f, 0.f};
    ah = mfma16(k0, aQ0h, ah);
    sh[nt] = mfma16(k1, aQ1h, ah);
    f32x4 al = {0.f, 0.f, 0.f, 0.f};
    al = mfma16(k0, aQ0l, al);
    sl[nt] = mfma16(k1, aQ1l, al);
  }
  __builtin_amdgcn_s_setprio(0);
  if (diagL) {
    const int rowl = wv * 16 + r0;
    #pragma unroll
    for (int nt = 0; nt < 4; ++nt)
      #pragma unroll
      for (int rr = 0; rr < 4; ++rr)
        if (nt * 16 + qh * 4 + rr > rowl) sl[nt][rr] = -1e30f;
  }
}

// O += P(prev) V(prev): aP fragments held in registers since prev iteration.
static __device__ __forceinline__ void pv16(
    const unsigned short* __restrict__ Vl, int r0, int qh,
    b16x8 aP0, b16x8 aP1, f32x4 (&o)[4])
{
  const int sw = r0 & 7;
  __builtin_amdgcn_s_setprio(1);
  #pragma unroll
  for (int dt = 0; dt < 4; ++dt) {
    const unsigned short* vr = Vl + (dt * 16 + r0) * 64;
    b16x8 bv0 = *(const b16x8*)(vr + ((qh ^ sw) * 8));
    b16x8 bv1 = *(const b16x8*)(vr + (((4 + qh) ^ sw) * 8));
    o[dt] = mfma16(aP0, bv0, o[dt]);
    o[dt] = mfma16(aP1, bv1, o[dt]);
  }
  __builtin_amdgcn_s_setprio(0);
}

// Dual-stream PV: V fragments read ONCE, feed both accumulators.
static __device__ __forceinline__ void pv2(
    const unsigned short* __restrict__ Vl, int r0, int qh,
    b16x8 aPh0, b16x8 aPh1, b16x8 aPl0, b16x8 aPl1,
    f32x4 (&oh)[4], f32x4 (&ol)[4])
{
  const int sw = r0 & 7;
  __builtin_amdgcn_s_setprio(1);
  #pragma unroll
  for (int dt = 0; dt < 4; ++dt) {
    const unsigned short* vr = Vl + (dt * 16 + r0) * 64;
    b16x8 bv0 = *(const b16x8*)(vr + ((qh ^ sw) * 8));
    b16x8 bv1 = *(const b16x8*)(vr + (((4 + qh) ^ sw) * 8));
    oh[dt] = mfma16(aPh0, bv0, oh[dt]);
    oh[dt] = mfma16(aPh1, bv1, oh[dt]);
    ol[dt] = mfma16(aPl0, bv0, ol[dt]);
    ol[dt] = mfma16(aPl1, bv1, ol[dt]);
  }
  __builtin_amdgcn_s_setprio(0);
}

// Static-shift softmax: p = exp2(s - FS). l-sum stays PER-LANE (psum f32x4);
// cross-lane reduce deferred to the epilogue.
static __device__ __forceinline__ void softmax_pack(
    f32x4 (&s)[4], f32x4& psum,
    unsigned short* __restrict__ Pl, int r0, int qh,
    b16x8& aP0, b16x8& aP1)
{
  const float FS = 32.0f;
  #pragma unroll
  for (int nt = 0; nt < 4; ++nt)
    #pragma unroll
    for (int rr = 0; rr < 4; ++rr)
      s[nt][rr] = __builtin_amdgcn_exp2f(s[nt][rr] - FS);
  psum += (s[0] + s[1]) + (s[2] + s[3]);
  // pack P (bf16 pairs), 4x ds_write_b64 into swizzled wave-private buffer
  const int xr = r0 & 7;
  unsigned short* pw = Pl + r0 * 64 + (qh & 1) * 4;
  #pragma unroll
  for (int nt = 0; nt < 4; ++nt) {
    u32x2 w;
    w.x = cvtpk(s[nt][0], s[nt][1]);
    w.y = cvtpk(s[nt][2], s[nt][3]);
    *(u32x2*)(pw + (((nt * 2 + (qh >> 1)) ^ xr) * 8)) = w;
  }
  // read back A-fragments for the deferred PV (per-wave DS ops are in-order)
  aP0 = *(const b16x8*)(Pl + r0 * 64 + ((qh ^ xr) * 8));
  aP1 = *(const b16x8*)(Pl + r0 * 64 + (((4 + qh) ^ xr) * 8));
}

static __device__ __forceinline__ void attn_epilogue(
    unsigned short* smem, const float* __restrict__ initw,
    float* __restrict__ out, int b, int h, int qt,
    int tid, int wv, int r0, int qh,
    f32x4 (&o)[4], f32x4 psum)
{
  // deferred l-reduction: horizontal + 2 shfls, once per stream
  float l = (psum[0] + psum[1]) + (psum[2] + psum[3]);
  l += __shfl_xor(l, 16);
  l += __shfl_xor(l, 32);
  __syncthreads();
  float* initL = (float*)smem;     // [64 c][65] = 16.6 KB (fits 32 KB region)
  const int cc = tid >> 2, qgrp = (tid & 3) * 16;
  const float* src = initw + (size_t)(b * CC + h * 64 + cc) * LQN;
  #pragma unroll
  for (int u = 0; u < 8; ++u) {
    int col = qt * 64 + qgrp + u * 2;
    if (col > LQN - 2) col = LQN - 2;
    f32x2 d = *(const f32x2*)(src + col);
    initL[cc * 65 + qgrp + u * 2]     = d.x;
    initL[cc * 65 + qgrp + u * 2 + 1] = d.y;
  }
  __syncthreads();
  #pragma unroll
  for (int r = 0; r < 4; ++r) {
    const float lq = __shfl(l, qh * 4 + r);   // l lives at lane r0 == q
    const int ql = wv * 16 + qh * 4 + r;
    const int qgl = qt * 64 + ql;
    if (qgl >= LQN) continue;
    const float invl = 1.0f / lq;
    float* dst = out + ((size_t)(b * LQN + qgl)) * CC + h * 64;
    #pragma unroll
    for (int dt = 0; dt < 4; ++dt)
      dst[dt * 16 + r0] = o[dt][r] * invl + initL[(dt * 16 + r0) * 65 + ql];
  }
}

// ---------------- Kernel 2: causal flash attention + residual ----------------
// 32 KB LDS (5 blocks/CU): K single buffer + V double buffer + P.
// Per iter: full __syncthreads (vmcnt drain: K(kt), V(kt-1) landed) ->
// issue V(kt) -> QK^T(kt) from Kb -> lgkmcnt(0) + RAW s_barrier (lane sync
// only; all waves' K reads consumed) -> issue K(kt+1) into Kb -> PV(kt-1)
// + softmax. K(kt+1) lands under the PV/softmax phase, drained next bar1.
// V keeps the one-tile lag (full iteration of cover). launch_bounds(256,5)
// caps VGPR at 102 (round-14: 104) so 5 blocks/CU are schedulable.
__global__ __launch_bounds__(256, 5) void attn_kernel(
    const unsigned short* __restrict__ qg, const unsigned short* __restrict__ kg,
    const unsigned short* __restrict__ vg, const float* __restrict__ initw,
    float* __restrict__ out)
{
  __shared__ __align__(16) unsigned short SM[16384];  // 32 KB total
  unsigned short* const Kb = SM;            // [0, 4096)  K single buffer
  unsigned short* const Vb = SM + 4096;     // [4096,12288) V double buffer
  unsigned short* const Pb = SM + 12288;    // [12288,16384) P per-wave

  const int bh = blockIdx.x;            // 0..63  (fast dim -> XCD = bh & 7)
  const int pi = blockIdx.y;            // 0..15
  const int hi = 31 - pi, lo = pi;
  const int b = bh >> 3, h = bh & 7;
  const int tid = threadIdx.x, lane = tid & 63, wv = tid >> 6;
  const int r0 = lane & 15, qh = lane >> 4;
  unsigned short* const Pw = Pb + wv * 1024;

  const size_t kqbase = (size_t)bh * LQN * DD;
  const size_t vbase  = ((size_t)(b * CC + h * 64)) * LL;

  // per-lane pre-swizzled staging sources; dest is linear in LDS.
  // staging geometry: each glds16 writes 512 halfwords; wave region wv*1024.
  const int l8 = lane >> 3, c8s = lane & 7;
  const int csw = c8s ^ l8;
  const unsigned short* kSrc = kg + kqbase + (size_t)(wv * 16 + l8) * DD + csw * 8;
  const unsigned short* vSrc = vg + vbase  + (size_t)(wv * 16 + l8) * LL + csw * 8;

  // Q fragments for both tiles
  b16x8 aQ0h, aQ1h, aQ0l, aQ1l;
  {
    int qrow = hi * 64 + wv * 16 + r0; if (qrow > LQN - 1) qrow = LQN - 1;
    const unsigned short* qp = qg + kqbase + (size_t)qrow * DD;
    aQ0h = *(const b16x8*)(qp + qh * 8);
    aQ1h = *(const b16x8*)(qp + 32 + qh * 8);
    qrow = lo * 64 + wv * 16 + r0;
    qp = qg + kqbase + (size_t)qrow * DD;
    aQ0l = *(const b16x8*)(qp + qh * 8);
    aQ1l = *(const b16x8*)(qp + 32 + qh * 8);
  }

  const f32x4 zero4 = {0.f, 0.f, 0.f, 0.f};
  f32x4 oh[4], ol[4];
  f32x4 psh = zero4, psl = zero4;    // per-lane partial l-sums
  #pragma unroll
  for (int dt = 0; dt < 4; ++dt) { oh[dt] = zero4; ol[dt] = zero4; }
  b16x8 aPh0, aPh1, aPl0, aPl1;   // deferred-PV A fragments

  int bi = 0;
  // prologue: K(0); V lags by one tile (V(t) issued at iteration t)
  glds16(kSrc,          Kb + wv * 1024);
  glds16(kSrc + 8 * DD, Kb + wv * 1024 + 512);
  kSrc += 64 * DD;

  for (int kt = 0; kt <= hi; ++kt) {
    __syncthreads();   // vmcnt drain: K(kt), V(kt-1) landed; Vb[bi^1] readers done
    glds16(vSrc,          Vb + (bi ^ 1) * 4096 + wv * 1024);
    glds16(vSrc + 8 * LL, Vb + (bi ^ 1) * 4096 + wv * 1024 + 512);
    vSrc += 64;

    if (kt <= lo) {
      // ---- dual-active: shared K/V fragment reads ----
      f32x4 sh[4], sl[4];
      qkt2(Kb, kt == lo, wv, r0, qh, aQ0h, aQ1h, aQ0l, aQ1l, sh, sl);
      asm volatile("s_waitcnt lgkmcnt(0)" ::: "memory");
      __builtin_amdgcn_s_barrier();          // Kb reads done; no vmcnt drain
      asm volatile("" ::: "memory");
      if (kt < hi) {
        glds16(kSrc,          Kb + wv * 1024);
        glds16(kSrc + 8 * DD, Kb + wv * 1024 + 512);
        kSrc += 64 * DD;
      }
      if (kt) pv2(Vb + bi * 4096, r0, qh, aPh0, aPh1, aPl0, aPl1, oh, ol);
      softmax_pack(sh, psh, Pw, r0, qh, aPh0, aPh1);
      softmax_pack(sl, psl, Pw, r0, qh, aPl0, aPl1);
    } else {
      // ---- solo-hi ----
      f32x4 sh[4];
      qkt16(Kb, kt == hi, wv, r0, qh, aQ0h, aQ1h, sh);
      asm volatile("s_waitcnt lgkmcnt(0)" ::: "memory");
      __builtin_amdgcn_s_barrier();          // Kb reads done; no vmcnt drain
      asm volatile("" ::: "memory");
      if (kt < hi) {
        glds16(kSrc,          Kb + wv * 1024);
        glds16(kSrc + 8 * DD, Kb + wv * 1024 + 512);
        kSrc += 64 * DD;
      }
      if (kt == lo + 1)
        pv2(Vb + bi * 4096, r0, qh, aPh0, aPh1, aPl0, aPl1, oh, ol); // PV(lo) both
      else
        pv16(Vb + bi * 4096, r0, qh, aPh0, aPh1, oh);                // PV_hi(kt-1)
      softmax_pack(sh, psh, Pw, r0, qh, aPh0, aPh1);
    }
    bi ^= 1;
  }
  __syncthreads();                 // V(hi) landed in Vb[bi]
  pv16(Vb + bi * 4096, r0, qh, aPh0, aPh1, oh);            // PV_hi(hi)

  attn_epilogue(SM, initw, out, b, h, hi, tid, wv, r0, qh, oh, psh);
  attn_epilogue(SM, initw, out, b, h, lo, tid, wv, r0, qh, ol, psl);
}

// ---------------- Kernel 3: LayerNorm over C, in-place on d_out --------------
__global__ __launch_bounds__(256) void ln_kernel(
    const float* __restrict__ gamma, const float* __restrict__ beta,
    float* __restrict__ out)
{
  const int row = blockIdx.x * 4 + ((int)threadIdx.x >> 6);
  const int lane = threadIdx.x & 63;
  if (row >= 8 * LQN) return;
  float* p = out + (size_t)row * CC;
  f32x4 x0 = *(const f32x4*)(p + lane * 8);
  f32x4 x1 = *(const f32x4*)(p + lane * 8 + 4);
  float s  = x0.x + x0.y + x0.z + x0.w + x1.x + x1.y + x1.z + x1.w;
  float sq = x0.x*x0.x + x0.y*x0.y + x0.z*x0.z + x0.w*x0.w
           + x1.x*x1.x + x1.y*x1.y + x1.z*x1.z + x1.w*x1.w;
  #pragma unroll
  for (int mm = 1; mm <= 32; mm <<= 1) {
    s  += __shfl_xor(s, mm);
    sq += __shfl_xor(sq, mm);
  }
  const float mu = s * (1.f / 512.f);
  const float var = sq * (1.f / 512.f) - mu * mu;
  const float rstd = rsqrtf(var + 1e-5f);
  f32x4 g0 = *(const f32x4*)(gamma + lane * 8);
  f32x4 g1 = *(const f32x4*)(gamma + lane * 8 + 4);
  f32x4 b0 = *(const f32x4*)(beta + lane * 8);
  f32x4 b1 = *(const f32x4*)(beta + lane * 8 + 4);
  x0 = (x0 - mu) * rstd * g0 + b0;
  x1 = (x1 - mu) * rstd * g1 + b1;
  *(f32x4*)(p + lane * 8)     = x0;
  *(f32x4*)(p + lane * 8 + 4) = x1;
}

extern "C" void kernel_launch(void* const* d_in, const int* in_sizes, int n_in,
                              void* d_out, int out_size, void* d_ws, size_t ws_size,
                              hipStream_t stream)
{
  const float* input = (const float*)d_in[0];
  const float* initw = (const float*)d_in[1];
  const float* qw    = (const float*)d_in[2];
  const float* kw    = (const float*)d_in[3];
  const float* vw    = (const float*)d_in[4];
  const float* gamma = (const float*)d_in[5];
  const float* beta  = (const float*)d_in[6];
  float* outp = (float*)d_out;

  unsigned short* q = (unsigned short*)d_ws;
  unsigned short* k = q + (16u * 1024u * 1024u / 2u);
  unsigned short* v = q + (32u * 1024u * 1024u / 2u);

  hipLaunchKernelGGL(conv_qkv_kernel, dim3(16, 8, 8), dim3(256), 0, stream,
                     input, qw, kw, vw, q, k, v);
  hipLaunchKernelGGL(attn_kernel, dim3(64, 16), dim3(256), 0, stream,
                     q, k, v, initw, outp);
  hipLaunchKernelGGL(ln_kernel, dim3(4092), dim3(256), 0, stream,
                     gamma, beta, outp);
}

// Round 16
// 127.033 us; speedup vs baseline: 4.2140x; 4.2140x over previous
//
#include <hip/hip_runtime.h>

#define LQN 2046
#define LL  2048
#define CC  512
#define DD  64

typedef float  f32x4 __attribute__((ext_vector_type(4)));
typedef float  f32x2 __attribute__((ext_vector_type(2)));
typedef __bf16 b16x8 __attribute__((ext_vector_type(8)));
typedef unsigned int u32x4 __attribute__((ext_vector_type(4)));
typedef unsigned int u32x2 __attribute__((ext_vector_type(2)));

static __device__ __forceinline__ unsigned short f2bf(float f) {
  union { float f; unsigned u; } v; v.f = f;
  return (unsigned short)((v.u + 0x7fffu + ((v.u >> 16) & 1u)) >> 16);
}

static __device__ __forceinline__ unsigned cvtpk(float lo, float hi) {
  unsigned r;
  asm("v_cvt_pk_bf16_f32 %0, %1, %2" : "=v"(r) : "v"(lo), "v"(hi));
  return r;
}

static __device__ __forceinline__ f32x4 mfma16(b16x8 a, b16x8 b, f32x4 c) {
  return __builtin_amdgcn_mfma_f32_16x16x32_bf16(a, b, c, 0, 0, 0);
}

// async global->LDS, 16B per lane; LDS dest = wave-uniform base + lane*16
static __device__ __forceinline__ void glds16(const unsigned short* g, unsigned short* l) {
  __builtin_amdgcn_global_load_lds(
      (const __attribute__((address_space(1))) unsigned int*)(g),
      (__attribute__((address_space(3))) unsigned int*)(l),
      16, 0, 0);
}

// ---------------- Kernel 1: grouped-conv QKV projections (MFMA) --------------
// Q is pre-scaled by log2(e)/sqrt(H) so attention scores land in exp2 domain.
__global__ __launch_bounds__(256) void conv_qkv_kernel(
    const float* __restrict__ in, const float* __restrict__ qw,
    const float* __restrict__ kw, const float* __restrict__ vw,
    unsigned short* __restrict__ qo, unsigned short* __restrict__ ko,
    unsigned short* __restrict__ vo)
{
  __shared__ __align__(16) unsigned short inT[130 * 72];  // [t][ci] bf16, pad 72
  __shared__ __align__(16) unsigned short buf[128 * 72];  // transpose buffer

  const int tile = blockIdx.x, g = blockIdx.y, b = blockIdx.z;
  const int t0 = tile * 128;
  const int tid = threadIdx.x;
  const int lane = tid & 63;
  const int wv = tid >> 6;
  const int r0 = lane & 15, qh = lane >> 4;

  {
    const int ci = tid & 63, ch = tid >> 6;
    const float* src = in + ((size_t)(b * CC + g * 64 + ci)) * LL;
    #pragma unroll
    for (int i = 0; i < 8; ++i) {
      int t = ch * 32 + i * 4;
      f32x4 d = *(const f32x4*)(src + t0 + t);
      inT[(t + 0) * 72 + ci] = f2bf(d.x);
      inT[(t + 1) * 72 + ci] = f2bf(d.y);
      inT[(t + 2) * 72 + ci] = f2bf(d.z);
      inT[(t + 3) * 72 + ci] = f2bf(d.w);
    }
    if (ch == 0) {
      #pragma unroll
      for (int e = 0; e < 2; ++e) {
        int t = 128 + e;
        int tg = t0 + t; if (tg > LL - 1) tg = LL - 1;
        inT[t * 72 + ci] = f2bf(src[tg]);
      }
    }
  }
  __syncthreads();

  const float* wptr[3] = {qw, kw, vw};
  const f32x4 zero4 = {0.f, 0.f, 0.f, 0.f};

  for (int p = 0; p < 3; ++p) {
    b16x8 aW[6];
    {
      const float* wb = wptr[p] + (size_t)(g * 64 + wv * 16 + r0) * 192;
      #pragma unroll
      for (int kc = 0; kc < 6; ++kc) {
        const int ktap = kc >> 1;
        const int cib = (kc & 1) * 32 + qh * 8;
        union { b16x8 v; unsigned short u[8]; } fr;
        #pragma unroll
        for (int j = 0; j < 8; ++j)
          fr.u[j] = f2bf(wb[(cib + j) * 3 + ktap]);
        aW[kc] = fr.v;
      }
    }
    f32x4 acc[8];
    #pragma unroll
    for (int nt = 0; nt < 8; ++nt) acc[nt] = zero4;
    #pragma unroll
    for (int kc = 0; kc < 6; ++kc) {
      const int radd = kc >> 1;
      const int colh = (kc & 1) * 32 + qh * 8;
      #pragma unroll
      for (int nt = 0; nt < 8; ++nt) {
        const int trow = nt * 16 + r0 + radd;
        b16x8 bI = *(const b16x8*)&inT[trow * 72 + colh];
        acc[nt] = mfma16(aW[kc], bI, acc[nt]);
      }
    }
    __syncthreads();
    if (p < 2) {
      const float qscl = (p == 0) ? 0.51006979f : 1.0f;  // log2(e)/sqrt(8)
      #pragma unroll
      for (int nt = 0; nt < 8; ++nt) {
        const int t = nt * 16 + r0;
        #pragma unroll
        for (int r = 0; r < 4; ++r)
          buf[t * 72 + wv * 16 + qh * 4 + r] = f2bf(acc[nt][r] * qscl);
      }
      __syncthreads();
      unsigned short* dst = (p == 0 ? qo : ko) +
          ((size_t)(b * 8 + g) * LQN + t0) * DD;
      #pragma unroll
      for (int it = 0; it < 4; ++it) {
        const int id = it * 256 + tid;
        const int t = id >> 3, c8 = id & 7;
        if (t0 + t < LQN)
          *(u32x4*)(dst + t * DD + c8 * 8) = *(const u32x4*)&buf[t * 72 + c8 * 8];
      }
    } else {
      #pragma unroll
      for (int nt = 0; nt < 8; ++nt) {
        const int t = nt * 16 + r0;
        #pragma unroll
        for (int r = 0; r < 4; ++r)
          buf[(wv * 16 + qh * 4 + r) * 136 + t] = f2bf(acc[nt][r]);
      }
      __syncthreads();
      unsigned short* dst = vo + ((size_t)(b * CC + g * 64)) * LL + t0;
      #pragma unroll
      for (int it = 0; it < 4; ++it) {
        const int id = it * 256 + tid;
        const int row = id >> 4, c16 = id & 15;
        *(u32x4*)(dst + (size_t)row * LL + c16 * 8) =
            *(const u32x4*)&buf[row * 136 + c16 * 8];
      }
    }
    __syncthreads();
  }
}

// ---------------- attention pieces (deferred-PV, static-shift softmax) -------
// S^T = mfma(K,Q): lane (r0,qh) holds S[q=wv*16+r0][kv=nt*16+qh*4+rr].
// Swizzle sw = krow&7 = r0&7 (nt*16 ≡ 0 mod 8).

static __device__ __forceinline__ void qkt16(
    const unsigned short* __restrict__ Kl, bool diag, int wv, int r0, int qh,
    b16x8 aQ0, b16x8 aQ1, f32x4 (&s)[4])
{
  const int sw = r0 & 7;
  __builtin_amdgcn_s_setprio(1);
  #pragma unroll
  for (int nt = 0; nt < 4; ++nt) {
    const unsigned short* kr = Kl + (nt * 16 + r0) * 64;
    b16x8 k0 = *(const b16x8*)(kr + ((qh ^ sw) * 8));
    b16x8 k1 = *(const b16x8*)(kr + (((4 + qh) ^ sw) * 8));
    f32x4 acc = {0.f, 0.f, 0.f, 0.f};
    acc = mfma16(k0, aQ0, acc);
    s[nt] = mfma16(k1, aQ1, acc);
  }
  __builtin_amdgcn_s_setprio(0);
  if (diag) {                                 // causal: mask kv_local > q_local
    const int rowl = wv * 16 + r0;
    #pragma unroll
    for (int nt = 0; nt < 4; ++nt)
      #pragma unroll
      for (int rr = 0; rr < 4; ++rr)
        if (nt * 16 + qh * 4 + rr > rowl) s[nt][rr] = -1e30f;
  }
}

// Dual-stream QK^T: K fragments read ONCE, feed both hi and lo MFMAs.
// (Dual iterations have kt <= lo < hi, so hi's diag never applies here.)
static __device__ __forceinline__ void qkt2(
    const unsigned short* __restrict__ Kl, bool diagL, int wv, int r0, int qh,
    b16x8 aQ0h, b16x8 aQ1h, b16x8 aQ0l, b16x8 aQ1l,
    f32x4 (&sh)[4], f32x4 (&sl)[4])
{
  const int sw = r0 & 7;
  __builtin_amdgcn_s_setprio(1);
  #pragma unroll
  for (int nt = 0; nt < 4; ++nt) {
    const unsigned short* kr = Kl + (nt * 16 + r0) * 64;
    b16x8 k0 = *(const b16x8*)(kr + ((qh ^ sw) * 8));
    b16x8 k1 = *(const b16x8*)(kr + (((4 + qh) ^ sw) * 8));
    f32x4 ah = {0.f, 0.f, 0.f, 0.f};
    ah = mfma16(k0, aQ0h, ah);
    sh[nt] = mfma16(k1, aQ1h, ah);
    f32x4 al = {0.f, 0.f, 0.f, 0.f};
    al = mfma16(k0, aQ0l, al);
    sl[nt] = mfma16(k1, aQ1l, al);
  }
  __builtin_amdgcn_s_setprio(0);
  if (diagL) {
    const int rowl = wv * 16 + r0;
    #pragma unroll
    for (int nt = 0; nt < 4; ++nt)
      #pragma unroll
      for (int rr = 0; rr < 4; ++rr)
        if (nt * 16 + qh * 4 + rr > rowl) sl[nt][rr] = -1e30f;
  }
}

// O += P(prev) V(prev): aP fragments held in registers since prev iteration.
static __device__ __forceinline__ void pv16(
    const unsigned short* __restrict__ Vl, int r0, int qh,
    b16x8 aP0, b16x8 aP1, f32x4 (&o)[4])
{
  const int sw = r0 & 7;
  __builtin_amdgcn_s_setprio(1);
  #pragma unroll
  for (int dt = 0; dt < 4; ++dt) {
    const unsigned short* vr = Vl + (dt * 16 + r0) * 64;
    b16x8 bv0 = *(const b16x8*)(vr + ((qh ^ sw) * 8));
    b16x8 bv1 = *(const b16x8*)(vr + (((4 + qh) ^ sw) * 8));
    o[dt] = mfma16(aP0, bv0, o[dt]);
    o[dt] = mfma16(aP1, bv1, o[dt]);
  }
  __builtin_amdgcn_s_setprio(0);
}

// Dual-stream PV: V fragments read ONCE, feed both accumulators.
static __device__ __forceinline__ void pv2(
    const unsigned short* __restrict__ Vl, int r0, int qh,
    b16x8 aPh0, b16x8 aPh1, b16x8 aPl0, b16x8 aPl1,
    f32x4 (&oh)[4], f32x4 (&ol)[4])
{
  const int sw = r0 & 7;
  __builtin_amdgcn_s_setprio(1);
  #pragma unroll
  for (int dt = 0; dt < 4; ++dt) {
    const unsigned short* vr = Vl + (dt * 16 + r0) * 64;
    b16x8 bv0 = *(const b16x8*)(vr + ((qh ^ sw) * 8));
    b16x8 bv1 = *(const b16x8*)(vr + (((4 + qh) ^ sw) * 8));
    oh[dt] = mfma16(aPh0, bv0, oh[dt]);
    oh[dt] = mfma16(aPh1, bv1, oh[dt]);
    ol[dt] = mfma16(aPl0, bv0, ol[dt]);
    ol[dt] = mfma16(aPl1, bv1, ol[dt]);
  }
  __builtin_amdgcn_s_setprio(0);
}

// Static-shift softmax: p = exp2(s - FS). l-sum stays PER-LANE (psum f32x4);
// cross-lane reduce deferred to the epilogue.
static __device__ __forceinline__ void softmax_pack(
    f32x4 (&s)[4], f32x4& psum,
    unsigned short* __restrict__ Pl, int r0, int qh,
    b16x8& aP0, b16x8& aP1)
{
  const float FS = 32.0f;
  #pragma unroll
  for (int nt = 0; nt < 4; ++nt)
    #pragma unroll
    for (int rr = 0; rr < 4; ++rr)
      s[nt][rr] = __builtin_amdgcn_exp2f(s[nt][rr] - FS);
  psum += (s[0] + s[1]) + (s[2] + s[3]);
  // pack P (bf16 pairs), 4x ds_write_b64 into swizzled wave-private buffer
  const int xr = r0 & 7;
  unsigned short* pw = Pl + r0 * 64 + (qh & 1) * 4;
  #pragma unroll
  for (int nt = 0; nt < 4; ++nt) {
    u32x2 w;
    w.x = cvtpk(s[nt][0], s[nt][1]);
    w.y = cvtpk(s[nt][2], s[nt][3]);
    *(u32x2*)(pw + (((nt * 2 + (qh >> 1)) ^ xr) * 8)) = w;
  }
  // read back A-fragments for the deferred PV (per-wave DS ops are in-order)
  aP0 = *(const b16x8*)(Pl + r0 * 64 + ((qh ^ xr) * 8));
  aP1 = *(const b16x8*)(Pl + r0 * 64 + (((4 + qh) ^ xr) * 8));
}

static __device__ __forceinline__ void attn_epilogue(
    unsigned short* smem, const float* __restrict__ initw,
    float* __restrict__ out, int b, int h, int qt,
    int tid, int wv, int r0, int qh,
    f32x4 (&o)[4], f32x4 psum)
{
  // deferred l-reduction: horizontal + 2 shfls, once per stream
  float l = (psum[0] + psum[1]) + (psum[2] + psum[3]);
  l += __shfl_xor(l, 16);
  l += __shfl_xor(l, 32);
  __syncthreads();
  float* initL = (float*)smem;     // [64 c][65]
  const int cc = tid >> 2, qgrp = (tid & 3) * 16;
  const float* src = initw + (size_t)(b * CC + h * 64 + cc) * LQN;
  #pragma unroll
  for (int u = 0; u < 8; ++u) {
    int col = qt * 64 + qgrp + u * 2;
    if (col > LQN - 2) col = LQN - 2;
    f32x2 d = *(const f32x2*)(src + col);
    initL[cc * 65 + qgrp + u * 2]     = d.x;
    initL[cc * 65 + qgrp + u * 2 + 1] = d.y;
  }
  __syncthreads();
  #pragma unroll
  for (int r = 0; r < 4; ++r) {
    const float lq = __shfl(l, qh * 4 + r);   // l lives at lane r0 == q
    const int ql = wv * 16 + qh * 4 + r;
    const int qgl = qt * 64 + ql;
    if (qgl >= LQN) continue;
    const float invl = 1.0f / lq;
    float* dst = out + ((size_t)(b * LQN + qgl)) * CC + h * 64;
    #pragma unroll
    for (int dt = 0; dt < 4; ++dt)
      dst[dt * 16 + r0] = o[dt][r] * invl + initL[(dt * 16 + r0) * 65 + ql];
  }
}

// ---------------- Kernel 2: causal flash attention + residual ----------------
// Pairing: block pi owns Q-tiles hi=31-pi, lo=pi (33 tile-computes, shared
// staging). Deferred-PV + static-shift softmax. Dual-active iterations use
// qkt2/pv2: K and V fragments read ONCE from LDS, feeding both streams.
// Grid (bh, pi): same-bh blocks share an XCD -> K/V from L2 (FETCH 172->54MB).
// Staging: each glds16 writes 512 halfwords; wave region wv*1024.
// NOTE: plain __launch_bounds__(256). Min-waves clauses ((256,4) r3, (256,5)
// r15) cap the register file below the ~104-reg natural allocation and spill
// catastrophically (r15: 93 -> 505 us, 1.3 GB scratch writes). Do not re-add.
__global__ __launch_bounds__(256) void attn_kernel(
    const unsigned short* __restrict__ qg, const unsigned short* __restrict__ kg,
    const unsigned short* __restrict__ vg, const float* __restrict__ initw,
    float* __restrict__ out)
{
  __shared__ __align__(16) unsigned short KV[2][8192]; // buf: K [0,4096) V [4096,8192)
  __shared__ __align__(16) unsigned short Pb[4][1024];

  const int bh = blockIdx.x;            // 0..63  (fast dim -> XCD = bh & 7)
  const int pi = blockIdx.y;            // 0..15
  const int hi = 31 - pi, lo = pi;
  const int b = bh >> 3, h = bh & 7;
  const int tid = threadIdx.x, lane = tid & 63, wv = tid >> 6;
  const int r0 = lane & 15, qh = lane >> 4;

  const size_t kqbase = (size_t)bh * LQN * DD;
  const size_t vbase  = ((size_t)(b * CC + h * 64)) * LL;

  // per-lane pre-swizzled staging sources; dest is linear in LDS.
  const int l8 = lane >> 3, c8s = lane & 7;
  const int csw = c8s ^ l8;
  const unsigned short* kSrc = kg + kqbase + (size_t)(wv * 16 + l8) * DD + csw * 8;
  const unsigned short* vSrc = vg + vbase  + (size_t)(wv * 16 + l8) * LL + csw * 8;

  // Q fragments for both tiles
  b16x8 aQ0h, aQ1h, aQ0l, aQ1l;
  {
    int qrow = hi * 64 + wv * 16 + r0; if (qrow > LQN - 1) qrow = LQN - 1;
    const unsigned short* qp = qg + kqbase + (size_t)qrow * DD;
    aQ0h = *(const b16x8*)(qp + qh * 8);
    aQ1h = *(const b16x8*)(qp + 32 + qh * 8);
    qrow = lo * 64 + wv * 16 + r0;
    qp = qg + kqbase + (size_t)qrow * DD;
    aQ0l = *(const b16x8*)(qp + qh * 8);
    aQ1l = *(const b16x8*)(qp + 32 + qh * 8);
  }

  const f32x4 zero4 = {0.f, 0.f, 0.f, 0.f};
  f32x4 oh[4], ol[4];
  f32x4 psh = zero4, psl = zero4;    // per-lane partial l-sums
  #pragma unroll
  for (int dt = 0; dt < 4; ++dt) { oh[dt] = zero4; ol[dt] = zero4; }
  b16x8 aPh0, aPh1, aPl0, aPl1;   // deferred-PV A fragments

  int bi = 0;
  // prologue: K(0) only; V lags by one tile (V(t) issued at iteration t)
  glds16(kSrc,          &KV[0][wv * 1024]);
  glds16(kSrc + 8 * DD, &KV[0][wv * 1024 + 512]);
  kSrc += 64 * DD;

  for (int kt = 0; kt <= hi; ++kt) {
    __syncthreads();   // Kbuf[bi]=K(kt), Vbuf[bi]=V(kt-1) landed; prev reads done
    if (kt < hi) {
      glds16(kSrc,          &KV[bi ^ 1][wv * 1024]);
      glds16(kSrc + 8 * DD, &KV[bi ^ 1][wv * 1024 + 512]);
      kSrc += 64 * DD;
    }
    glds16(vSrc,          &KV[bi ^ 1][4096 + wv * 1024]);
    glds16(vSrc + 8 * LL, &KV[bi ^ 1][4096 + wv * 1024 + 512]);
    vSrc += 64;

    if (kt <= lo) {
      // ---- dual-active: shared K/V fragment reads ----
      f32x4 sh[4], sl[4];
      qkt2(&KV[bi][0], kt == lo, wv, r0, qh,
           aQ0h, aQ1h, aQ0l, aQ1l, sh, sl);
      if (kt) pv2(&KV[bi][4096], r0, qh, aPh0, aPh1, aPl0, aPl1, oh, ol);
      softmax_pack(sh, psh, Pb[wv], r0, qh, aPh0, aPh1);
      softmax_pack(sl, psl, Pb[wv], r0, qh, aPl0, aPl1);
    } else {
      // ---- solo-hi ----
      f32x4 sh[4];
      qkt16(&KV[bi][0], kt == hi, wv, r0, qh, aQ0h, aQ1h, sh);
      if (kt == lo + 1)
        pv2(&KV[bi][4096], r0, qh, aPh0, aPh1, aPl0, aPl1, oh, ol); // PV(lo) both
      else
        pv16(&KV[bi][4096], r0, qh, aPh0, aPh1, oh);                // PV_hi(kt-1)
      softmax_pack(sh, psh, Pb[wv], r0, qh, aPh0, aPh1);
    }
    bi ^= 1;
  }
  __syncthreads();                 // V(hi) landed in Vbuf[bi]
  pv16(&KV[bi][4096], r0, qh, aPh0, aPh1, oh);             // PV_hi(hi)

  attn_epilogue(&KV[0][0], initw, out, b, h, hi, tid, wv, r0, qh, oh, psh);
  attn_epilogue(&KV[0][0], initw, out, b, h, lo, tid, wv, r0, qh, ol, psl);
}

// ---------------- Kernel 3: LayerNorm over C, in-place on d_out --------------
__global__ __launch_bounds__(256) void ln_kernel(
    const float* __restrict__ gamma, const float* __restrict__ beta,
    float* __restrict__ out)
{
  const int row = blockIdx.x * 4 + ((int)threadIdx.x >> 6);
  const int lane = threadIdx.x & 63;
  if (row >= 8 * LQN) return;
  float* p = out + (size_t)row * CC;
  f32x4 x0 = *(const f32x4*)(p + lane * 8);
  f32x4 x1 = *(const f32x4*)(p + lane * 8 + 4);
  float s  = x0.x + x0.y + x0.z + x0.w + x1.x + x1.y + x1.z + x1.w;
  float sq = x0.x*x0.x + x0.y*x0.y + x0.z*x0.z + x0.w*x0.w
           + x1.x*x1.x + x1.y*x1.y + x1.z*x1.z + x1.w*x1.w;
  #pragma unroll
  for (int mm = 1; mm <= 32; mm <<= 1) {
    s  += __shfl_xor(s, mm);
    sq += __shfl_xor(sq, mm);
  }
  const float mu = s * (1.f / 512.f);
  const float var = sq * (1.f / 512.f) - mu * mu;
  const float rstd = rsqrtf(var + 1e-5f);
  f32x4 g0 = *(const f32x4*)(gamma + lane * 8);
  f32x4 g1 = *(const f32x4*)(gamma + lane * 8 + 4);
  f32x4 b0 = *(const f32x4*)(beta + lane * 8);
  f32x4 b1 = *(const f32x4*)(beta + lane * 8 + 4);
  x0 = (x0 - mu) * rstd * g0 + b0;
  x1 = (x1 - mu) * rstd * g1 + b1;
  *(f32x4*)(p + lane * 8)     = x0;
  *(f32x4*)(p + lane * 8 + 4) = x1;
}

extern "C" void kernel_launch(void* const* d_in, const int* in_sizes, int n_in,
                              void* d_out, int out_size, void* d_ws, size_t ws_size,
                              hipStream_t stream)
{
  const float* input = (const float*)d_in[0];
  const float* initw = (const float*)d_in[1];
  const float* qw    = (const float*)d_in[2];
  const float* kw    = (const float*)d_in[3];
  const float* vw    = (const float*)d_in[4];
  const float* gamma = (const float*)d_in[5];
  const float* beta  = (const float*)d_in[6];
  float* outp = (float*)d_out;

  unsigned short* q = (unsigned short*)d_ws;
  unsigned short* k = q + (16u * 1024u * 1024u / 2u);
  unsigned short* v = q + (32u * 1024u * 1024u / 2u);

  hipLaunchKernelGGL(conv_qkv_kernel, dim3(16, 8, 8), dim3(256), 0, stream,
                     input, qw, kw, vw, q, k, v);
  hipLaunchKernelGGL(attn_kernel, dim3(64, 16), dim3(256), 0, stream,
                     q, k, v, initw, outp);
  hipLaunchKernelGGL(ln_kernel, dim3(4092), dim3(256), 0, stream,
                     gamma, beta, outp);
}